// Round 1
// baseline (2876.331 us; speedup 1.0000x reference)
//
#include <hip/hip_runtime.h>
#include <math.h>

#define NN 128
#define SS 129          // LDS row stride (pad: conflict-free rows AND columns)
#define BLK 128

__device__ __forceinline__ double blockReduceSum(double v, double* red, int tid) {
  for (int off = 32; off > 0; off >>= 1) v += __shfl_down(v, off, 64);
  __syncthreads();                      // protect red[] from previous round
  if ((tid & 63) == 0) red[tid >> 6] = v;
  __syncthreads();
  return red[0] + red[1];
}

__device__ __forceinline__ float startvec(int i, int k) {
  unsigned h = (unsigned)(i * 1664525 + k * 1013904223 + 12345);
  h ^= h >> 13; h *= 2654435761u; h ^= h >> 16;
  return ((float)(h & 0xFFFFFFu) * (1.0f / 16777216.0f)) - 0.5f;
}

extern "C" __global__ void __launch_bounds__(BLK)
holo_kernel(const float* __restrict__ A, const float* __restrict__ F,
            const float* __restrict__ swg, const float* __restrict__ curv,
            const float* __restrict__ W1, const float* __restrict__ Bb1,
            const float* __restrict__ W2, const float* __restrict__ Bb2,
            const float* __restrict__ OW1, const float* __restrict__ OB1,
            const float* __restrict__ OW2, const float* __restrict__ OB2,
            float* __restrict__ out, int B)
{
  __shared__ float  mat[NN * SS];                       // 66048 B (A -> L -> reflectors -> invit ws)
  __shared__ double dd[NN], ee[NN], ee2[NN], tvec[NN], tauv[NN];
  __shared__ double red[2];
  __shared__ double sc[8];
  __shared__ double lam[20];
  __shared__ double blo[17], bhi[17];
  __shared__ int    bcnt[119];
  __shared__ float  ubuf[NN], pbuf[NN], qbuf[NN];
  __shared__ float  invdeg[NN], svec[NN], gvv[NN], hvv[NN], cw[NN];
  __shared__ double ssv[16], dred[16];
  __shared__ float  msv[64], pool[16], comb[NN], hbuf[NN], zrow[16];

  const int  tid = threadIdx.x;
  const long b   = blockIdx.x;
  const float* Ab = A + b * (long)(NN * NN);
  const float* Fb = F + b * (long)(NN * 64);

  // ---------------- load A into LDS ----------------
  for (int idx = tid; idx < NN * NN; idx += BLK)
    mat[(idx >> 7) * SS + (idx & 127)] = Ab[idx];
  __syncthreads();

  // ---------------- degrees ----------------
  {
    double s = 0.0;
    const float* row = &mat[tid * SS];
    for (int j = 0; j < NN; ++j) s += (double)row[j];
    const double dg = s + 1e-8;
    invdeg[tid] = (float)(1.0 / dg);
    svec[tid]   = (float)(1.0 / sqrt(dg));
  }
  __syncthreads();
  // g = R^T 1  (A symmetric -> row dot with invdeg)
  {
    double g = 0.0;
    const float* row = &mat[tid * SS];
    for (int j = 0; j < NN; ++j) g += (double)row[j] * (double)invdeg[j];
    gvv[tid] = (float)g;
  }
  __syncthreads();
  // h = R^T g
  {
    double h = 0.0;
    const float* row = &mat[tid * SS];
    for (int j = 0; j < NN; ++j) h += (double)row[j] * (double)(gvv[j] * invdeg[j]);
    hvv[tid] = (float)h;
  }
  if (tid == 0) {
    const float a0 = swg[0], a1 = swg[1], a2 = swg[2];
    const float mx = fmaxf(a0, fmaxf(a1, a2));
    const float e0 = expf(a0 - mx), e1 = expf(a1 - mx), e2v = expf(a2 - mx);
    const float s = e0 + e1 + e2v;
    sc[0] = (double)(e0 / s); sc[1] = (double)(e1 / s); sc[2] = (double)(e2v / s);
  }
  __syncthreads();
  cw[tid] = ((float)sc[0] + (float)sc[1] * gvv[tid] + (float)sc[2] * hvv[tid]) * (1.0f / NN);
  __syncthreads();
  // ms[d] = sum_n cw[n] * F[n][d]   (two 64-row halves)
  {
    const int d = tid & 63, half = tid >> 6;
    float acc = 0.0f;
    const float* fb = Fb + half * 64 * 64;
    for (int n = 0; n < 64; ++n) acc = fmaf(cw[half * 64 + n], fb[n * 64 + d], acc);
    if (half) pbuf[d] = acc;
    __syncthreads();
    if (!half) msv[d] = acc + pbuf[d];
  }
  __syncthreads();

  // ---------------- L = I - D^-1/2 A D^-1/2 (in place) ----------------
  for (int idx = tid; idx < NN * NN; idx += BLK) {
    const int r = idx >> 7, c = idx & 127;
    const float v = mat[r * SS + c];
    const float l = (v * svec[r]) * svec[c];
    mat[r * SS + c] = (r == c) ? (1.0f - l) : (-l);
  }
  __syncthreads();

  // ---------------- Householder tridiagonalization ----------------
  for (int k = 0; k < NN - 2; ++k) {
    const int m = NN - 1 - k;
    float  xi = 0.0f;
    double part = 0.0;
    if (tid < m) {
      xi = mat[(k + 1 + tid) * SS + k];
      if (tid > 0) part = (double)xi * (double)xi;
    }
    const double sig = blockReduceSum(part, red, tid);
    if (tid == 0) {
      const double alpha = (double)mat[(k + 1) * SS + k];
      dd[k] = (double)mat[k * SS + k];
      double beta, tau, scl;
      if (sig <= 0.0) { beta = alpha; tau = 0.0; scl = 0.0; }
      else {
        beta = -copysign(sqrt(alpha * alpha + sig), alpha);
        tau  = (beta - alpha) / beta;
        scl  = 1.0 / (alpha - beta);
      }
      ee[k] = beta; tauv[k] = tau; sc[0] = tau; sc[1] = scl;
    }
    __syncthreads();
    const double tau = sc[0];
    if (tid < m) {
      const float u = (tid == 0) ? 1.0f : (float)((double)xi * sc[1]);
      ubuf[tid] = u;
      mat[(k + 1 + tid) * SS + k] = u;      // keep reflector for Q^T*1 sweep
    }
    __syncthreads();
    if (tau != 0.0) {                        // uniform branch
      if (tid < m) {
        const float* row = &mat[(k + 1 + tid) * SS + (k + 1)];
        float a0 = 0.0f, a1 = 0.0f;
        int j = 0;
        for (; j + 1 < m; j += 2) {
          a0 = fmaf(row[j],     ubuf[j],     a0);
          a1 = fmaf(row[j + 1], ubuf[j + 1], a1);
        }
        if (j < m) a0 = fmaf(row[j], ubuf[j], a0);
        pbuf[tid] = (float)tau * (a0 + a1);  // p = tau*A*u
      }
      __syncthreads();
      double up = 0.0;
      if (tid < m) up = (double)ubuf[tid] * (double)pbuf[tid];
      const double upd = blockReduceSum(up, red, tid);
      if (tid == 0) sc[2] = 0.5 * tau * upd;
      __syncthreads();
      const float K = (float)sc[2];
      if (tid < m) qbuf[tid] = fmaf(-K, ubuf[tid], pbuf[tid]);
      __syncthreads();
      if (tid < m) {                         // A -= u q^T + q u^T (full symmetric block)
        const float ui = ubuf[tid], qi = qbuf[tid];
        float* row = &mat[(k + 1 + tid) * SS + (k + 1)];
        for (int j = 0; j < m; ++j)
          row[j] -= ui * qbuf[j] + qi * ubuf[j];
      }
      __syncthreads();
    }
  }
  if (tid == 0) {
    dd[NN - 2] = (double)mat[(NN - 2) * SS + (NN - 2)];
    ee[NN - 2] = (double)mat[(NN - 1) * SS + (NN - 2)];
    dd[NN - 1] = (double)mat[(NN - 1) * SS + (NN - 1)];
    tauv[NN - 2] = 0.0;
  }
  __syncthreads();

  // ---------------- t = Q^T * ones (single wave, forward reflector sweep) ----------------
  tvec[tid] = 1.0;
  __syncthreads();
  if (tid < 64) {
    for (int k = 0; k < NN - 2; ++k) {
      const int m = NN - 1 - k;
      const double tau = tauv[k];
      if (tau != 0.0) {
        double part = 0.0, u0 = 0.0, u1 = 0.0;
        const int i0 = tid, i1 = tid + 64;
        if (i0 < m) { u0 = (double)mat[(k + 1 + i0) * SS + k]; part += u0 * tvec[k + 1 + i0]; }
        if (i1 < m) { u1 = (double)mat[(k + 1 + i1) * SS + k]; part += u1 * tvec[k + 1 + i1]; }
        for (int off = 32; off > 0; off >>= 1) part += __shfl_down(part, off, 64);
        const double tw = tau * __shfl(part, 0, 64);
        if (i0 < m) tvec[k + 1 + i0] -= tw * u0;
        if (i1 < m) tvec[k + 1 + i1] -= tw * u1;
      }
    }
  }
  __syncthreads();

  // ---------------- bisection (multisection x7, 12 rounds) for lambda_0..16 ----------------
  if (tid < NN - 1) ee2[tid] = ee[tid] * ee[tid];
  if (tid == 0) {
    double lo = 1e300, hi = -1e300;
    for (int i = 0; i < NN; ++i) {
      const double r = ((i > 0) ? fabs(ee[i - 1]) : 0.0) + ((i < NN - 1) ? fabs(ee[i]) : 0.0);
      lo = fmin(lo, dd[i] - r);
      hi = fmax(hi, dd[i] + r);
    }
    sc[0] = lo - 1e-6; sc[1] = hi + 1e-6;
  }
  __syncthreads();
  if (tid < 17) { blo[tid] = sc[0]; bhi[tid] = sc[1]; }
  __syncthreads();
  for (int round = 0; round < 12; ++round) {
    if (tid < 119) {
      const int ke = tid / 7, j = tid % 7;
      const double lo = blo[ke], hi = bhi[ke];
      const double x = lo + (hi - lo) * ((double)(j + 1) * 0.125);
      int cnt = 0;
      double pm = 1.0, p = dd[0] - x;          // scaled charpoly Sturm, division-free
      if (p < 0.0) cnt++;
      for (int i = 1; i < NN; ++i) {
        const double pn = (dd[i] - x) * p - ee2[i - 1] * pm;
        pm = p; p = pn;
        if ((p < 0.0) != (pm < 0.0)) cnt++;
        const double ap = fabs(p);
        if (ap > 1e100)                { p *= 1e-100; pm *= 1e-100; }
        else if (ap < 1e-100 && ap > 0.0) { p *= 1e100;  pm *= 1e100; }
      }
      bcnt[tid] = cnt;
    }
    __syncthreads();
    if (tid < 17) {
      const double lo = blo[tid], hi = bhi[tid];
      const double w8 = (hi - lo) * 0.125;
      double nlo = lo, nhi = hi;
      for (int jj = 0; jj < 7; ++jj) {
        const double x = lo + w8 * (double)(jj + 1);
        if (bcnt[tid * 7 + jj] <= tid) nlo = x; else { nhi = x; break; }
      }
      blo[tid] = nlo; bhi[tid] = nhi;
    }
    __syncthreads();
  }
  if (tid < 17) lam[tid] = 0.5 * (blo[tid] + bhi[tid]);
  __syncthreads();

  // ---------------- inverse iteration on T (lanes 0..15 -> eigen idx 1..16) ----------------
  float* bu0 = mat;                 // reuse matrix LDS; stripes padded to 17
  float* bu1 = mat + NN * 17;
  float* bu2 = mat + 2 * NN * 17;
  float* byv = mat + 3 * NN * 17;

  if (tid < 16) {
    const double lk = lam[tid + 1];
    for (int it = 0; it < 2; ++it) {
      float beta = (float)(dd[0] - lk);
      float gam  = (float)ee[0];
      float r    = (it == 0) ? startvec(0, tid) : byv[0 * 17 + tid];
      for (int i = 1; i < NN; ++i) {
        const float ai = (float)ee[i - 1];
        const float bi = (float)(dd[i] - lk);
        const float ci = (i < NN - 1) ? (float)ee[i] : 0.0f;
        const float ri = (it == 0) ? startvec(i, tid) : byv[i * 17 + tid];
        if (fabsf(beta) >= fabsf(ai)) {
          float piv = beta;
          if (piv == 0.0f) piv = 1e-25f;
          const float mm = ai / piv;
          bu0[(i - 1) * 17 + tid] = piv;
          bu1[(i - 1) * 17 + tid] = gam;
          bu2[(i - 1) * 17 + tid] = 0.0f;
          byv[(i - 1) * 17 + tid] = r;
          beta = bi - mm * gam;  gam = ci;  r = ri - mm * r;
        } else {                                  // pivot swap
          const float mm = beta / ai;
          bu0[(i - 1) * 17 + tid] = ai;
          bu1[(i - 1) * 17 + tid] = bi;
          bu2[(i - 1) * 17 + tid] = ci;
          byv[(i - 1) * 17 + tid] = ri;
          const float nb = gam - mm * bi;
          gam = -mm * ci;  beta = nb;  r = r - mm * ri;
        }
      }
      if (beta == 0.0f) beta = 1e-25f;
      bu0[(NN - 1) * 17 + tid] = beta;
      bu1[(NN - 1) * 17 + tid] = 0.0f;
      bu2[(NN - 1) * 17 + tid] = 0.0f;
      byv[(NN - 1) * 17 + tid] = r;
      float y1 = 0.0f, y2 = 0.0f;
      for (int i = NN - 1; i >= 0; --i) {
        const float yy = (byv[i * 17 + tid] - bu1[i * 17 + tid] * y1 - bu2[i * 17 + tid] * y2)
                         / bu0[i * 17 + tid];
        byv[i * 17 + tid] = yy;
        y2 = y1; y1 = yy;
      }
      double nrm = 0.0;
      for (int i = 0; i < NN; ++i) { const double v = (double)byv[i * 17 + tid]; nrm += v * v; }
      const double inv = 1.0 / sqrt(nrm);
      for (int i = 0; i < NN; ++i) byv[i * 17 + tid] = (float)((double)byv[i * 17 + tid] * inv);
    }
  }
  __syncthreads();

  // ---------------- MGS (handles clustered eigenvalues) ----------------
  for (int kk = 1; kk < 16; ++kk) {
    const int j = tid >> 3, s8 = tid & 7;
    double part = 0.0;
    if (j < kk)
      for (int i = s8 * 16; i < s8 * 16 + 16; ++i)
        part += (double)byv[i * 17 + j] * (double)byv[i * 17 + kk];
    for (int off = 4; off > 0; off >>= 1) part += __shfl_down(part, off, 8);
    __syncthreads();
    if (s8 == 0 && j < kk) dred[j] = part;
    __syncthreads();
    {
      double acc = (double)byv[tid * 17 + kk];
      for (int j2 = 0; j2 < kk; ++j2) acc -= dred[j2] * (double)byv[tid * 17 + j2];
      byv[tid * 17 + kk] = (float)acc;
    }
    __syncthreads();
    double p2; { const double v = (double)byv[tid * 17 + kk]; p2 = v * v; }
    const double n2 = blockReduceSum(p2, red, tid);
    byv[tid * 17 + kk] = (float)((double)byv[tid * 17 + kk] / sqrt(n2));
    __syncthreads();
  }

  // ---------------- s_k = t . y_k ; pooled = softmax(-lam)*s ----------------
  {
    const int j = tid >> 3, s8 = tid & 7;
    double part = 0.0;
    for (int i = s8 * 16; i < s8 * 16 + 16; ++i)
      part += tvec[i] * (double)byv[i * 17 + j];
    for (int off = 4; off > 0; off >>= 1) part += __shfl_down(part, off, 8);
    if (s8 == 0) ssv[j] = part;
  }
  __syncthreads();
  if (tid == 0) {
    float lv[16], ev[16];
    float mx = -1e30f;
    for (int i = 0; i < 16; ++i) { lv[i] = (float)lam[i + 1]; mx = fmaxf(mx, -lv[i]); }
    float se = 0.0f;
    for (int i = 0; i < 16; ++i) { ev[i] = expf(-lv[i] - mx); se += ev[i]; }
    for (int i = 0; i < 16; ++i) pool[i] = (ev[i] / se) * (float)ssv[i];
  }
  __syncthreads();

  // ---------------- MLPs + outputs ----------------
  {
    float acc = Bb1[tid];
    for (int i = 0; i < 16; ++i) acc = fmaf(pool[i], W1[i * 128 + tid], acc);
    hbuf[tid] = fmaxf(acc, 0.0f);
  }
  __syncthreads();
  if (tid < 64) {
    float acc = Bb2[tid];
    for (int i = 0; i < 128; ++i) acc = fmaf(hbuf[i], W2[i * 64 + tid], acc);
    comb[tid] = acc;                 // spectral
  } else {
    comb[tid] = msv[tid - 64];       // ms
  }
  __syncthreads();
  {
    float acc = OB1[tid];
    for (int i = 0; i < 128; ++i) acc = fmaf(comb[i], OW1[i * 128 + tid], acc);
    hbuf[tid] = fmaxf(acc, 0.0f);
  }
  __syncthreads();
  if (tid < 16) {
    float acc = OB2[tid];
    for (int i = 0; i < 128; ++i) acc = fmaf(hbuf[i], OW2[i * 16 + tid], acc);
    zrow[tid] = acc;
  }
  __syncthreads();

  const long zeoff = (long)B * 16;
  const long spoff = (long)B * 32;
  const long svoff = (long)B * 32 + (long)B * 64;
  const long coff  = svoff + (long)B * 16;

  if (tid == 0) {
    const float c = 1.0f / (1.0f + expf(-curv[0]));
    float nrm = 0.0f;
    for (int i = 0; i < 16; ++i) nrm += zrow[i] * zrow[i];
    nrm = sqrtf(nrm);
    const float max_r = 0.95f / sqrtf(c);
    sc[3] = (double)fminf(1.0f, max_r / (nrm + 1e-12f));
    if (b == 0) out[coff] = c;
  }
  __syncthreads();
  if (tid < 16) {
    const float fac = (float)sc[3];
    out[b * 16 + tid]          = zrow[tid] * fac;   // z
    out[zeoff + b * 16 + tid]  = zrow[tid];         // z_euclidean
    out[svoff + b * 16 + tid]  = (float)lam[tid + 1]; // sel_vals
  }
  if (tid < 64) out[spoff + b * 64 + tid] = comb[tid]; // spectral
}

extern "C" void kernel_launch(void* const* d_in, const int* in_sizes, int n_in,
                              void* d_out, int out_size, void* d_ws, size_t ws_size,
                              hipStream_t stream) {
  const float* A    = (const float*)d_in[0];
  const float* F    = (const float*)d_in[1];
  const float* swg  = (const float*)d_in[2];
  const float* curv = (const float*)d_in[3];
  const float* W1   = (const float*)d_in[4];
  const float* Bb1  = (const float*)d_in[5];
  const float* W2   = (const float*)d_in[6];
  const float* Bb2  = (const float*)d_in[7];
  const float* OW1  = (const float*)d_in[8];
  const float* OB1  = (const float*)d_in[9];
  const float* OW2  = (const float*)d_in[10];
  const float* OB2  = (const float*)d_in[11];
  float* out = (float*)d_out;
  const int B = in_sizes[0] / (128 * 128);

  holo_kernel<<<dim3(B), dim3(BLK), 0, stream>>>(
      A, F, swg, curv, W1, Bb1, W2, Bb2, OW1, OB1, OW2, OB2, out, B);
}